// Round 13
// baseline (82.351 us; speedup 1.0000x reference)
//
#include <hip/hip_runtime.h>

#define Bn 2
#define Cn 3
#define Hn 160
#define Wn 160
#define SPANc 11
#define Kc 23
#define HWn (Hn * Wn)
#define PW 182                 // padded dim: 160 + 2*11
#define PP (PW * PW)
#define LAMc 0.15f
#define INVN (1.0f / (float)(Bn * HWn))
#define TJ 32                  // j-tile width (= lanes 0..31)
#define Gc 4                   // centers per thread (vertical)
#define TI 32                  // i-tile height = 8 ty-groups * Gc
#define CEXP (-0.72134752f)    // -0.5 * log2(e)
#define CX   (14.42695041f)    // 20 * 0.72134752  (cross-term scale)
#define CA   (0.72134752f)
#define NPREP ((Bn * PP + 255) / 256)   // 259 prep blocks
#define NCELL 64               // spread accumulator cells (256 B apart)
#define CELLSTRIDE 64          // floats between cells

__device__ __forceinline__ float wave_reduce64(float v) {
#pragma unroll
    for (int off = 32; off > 0; off >>= 1) v += __shfl_down(v, off, 64);
    return v;
}

// Fused prep: zero halo + softmax interior + CE block-partials (pre-scaled) +
// zero the 64 spread cells. UNPACKED fp32 records (no bf16 quantization):
//   gP = (p0, p1, p2, mB)  with mB = -72.13*sum(p^2)
//   gQ = (q0, q1, q2, 0)   with q = src*y
// exp2 identity: -0.7213*sum((c-10p)^2) = 14.427*sum(c*p) - A - B.
__global__ __launch_bounds__(256) void prep_kernel(
    const float* __restrict__ logit, const int* __restrict__ target,
    const float* __restrict__ image, const float* __restrict__ srcmap,
    const float* __restrict__ dstmap, float4* __restrict__ gP,
    float4* __restrict__ gQ, float4* __restrict__ cvec,
    float* __restrict__ pc, float* __restrict__ cells)
{
    int idx = blockIdx.x * 256 + threadIdx.x;
    float ce = 0.0f;
    if (idx < NCELL) cells[idx * CELLSTRIDE] = 0.0f;   // gcrf runs after (stream order)
    if (idx < Bn * PP) {
        int b   = idx / PP;
        int rem = idx - b * PP;
        int ip  = rem / PW;
        int jp  = rem - ip * PW;
        int i = ip - SPANc, j = jp - SPANc;
        if ((unsigned)i < (unsigned)Hn && (unsigned)j < (unsigned)Wn) {
            int r = i * Wn + j;
            int p = b * HWn + r;
            const float* lg = logit + (size_t)b * Cn * HWn + r;
            float l0 = lg[0], l1 = lg[HWn], l2 = lg[2 * HWn];
            float m = fmaxf(l0, fmaxf(l1, l2));
            float e0 = __expf(l0 - m), e1 = __expf(l1 - m), e2 = __expf(l2 - m);
            float s = e0 + e1 + e2;
            float inv = 1.0f / s;
            float y0 = e0 * inv, y1 = e1 * inv, y2 = e2 * inv;
            float lse = m + __logf(s);

            const float* im = image + (size_t)b * 3 * HWn + r;
            float p0 = im[0], p1 = im[HWn], p2 = im[2 * HWn];
            float sv = srcmap[p];
            float dv = dstmap[p];

            float B = (p0 * p0 + p1 * p1 + p2 * p2) * (100.0f * CA);
            gP[idx] = make_float4(p0, p1, p2, -B);
            gQ[idx] = make_float4(sv * y0, sv * y1, sv * y2, 0.0f);

            float md = LAMc * (1.0f - dv) * INVN;
            cvec[p] = make_float4(md * (1.0f - y0), md * (1.0f - y1),
                                  md * (1.0f - y2), 0.0f);

            int t = target[p];
            float lt = (t == 0) ? l0 : ((t == 1) ? l1 : l2);
            ce = (lse - lt) * dv * INVN;
        } else {
            gP[idx] = make_float4(0.f, 0.f, 0.f, 0.f);
            gQ[idx] = make_float4(0.f, 0.f, 0.f, 0.f);   // q=0 kills halo taps
        }
    }

    float v = wave_reduce64(ce);
    __shared__ float wsum[4];
    int tid = threadIdx.x;
    if ((tid & 63) == 0) wsum[tid >> 6] = v;
    __syncthreads();
    if (tid == 0) pc[blockIdx.x] = wsum[0] + wsum[1] + wsum[2] + wsum[3];
}

// One tap (proven scalar form, no unpack). Non-XY: kA-factored — k = exp2(c.p+mB);
// per-center exp2(mA) applied once in the epilogue. XY: exact form + xy term.
template<bool XY>
__device__ __forceinline__ void tap(float p0, float p1, float p2, float mB,
                                    float q0, float q1, float q2,
                                    float c0s, float c1s, float c2s, float mA,
                                    bool xy_on, float dy2, float dxv,
                                    float& e0, float& e1, float& e2)
{
    float e = fmaf(c0s, p0, fmaf(c1s, p1, fmaf(c2s, p2, mB)));
    float k;
    if constexpr (XY) {
        k = __builtin_amdgcn_exp2f(e + mA);
        if (xy_on) k += __builtin_amdgcn_exp2f(fmaf(dxv, dxv, dy2) * CEXP);
    } else {
        k = __builtin_amdgcn_exp2f(e);
    }
    e0 = fmaf(k, q0, e0);
    e1 = fmaf(k, q1, e1);
    e2 = fmaf(k, q2, e2);
}

template<bool XY>
__device__ __forceinline__ void row_taps(float4 P, float4 Q, int r,
    const float* c0s, const float* c1s, const float* c2s, const float* mA,
    bool xy_on, float dy2, float fi0, float eg[Gc][3], int clo, int chi)
{
    float dxb = XY ? (fi0 - (fi0 + (float)(r - SPANc)) * (1.0f / 6.0f)) : 0.0f;
#pragma unroll
    for (int c = 0; c < Gc; ++c) {
        if (c < clo || c > chi) continue;
        tap<XY>(P.x, P.y, P.z, P.w, Q.x, Q.y, Q.z,
                c0s[c], c1s[c], c2s[c], mA[c],
                xy_on, dy2, dxb + (float)c, eg[c][0], eg[c][1], eg[c][2]);
    }
}

// 3-phase window loop reading rows DIRECTLY from global (L2-resident gP/gQ).
// Bases point at this thread's local row 0; rows stride PW. Lane-consecutive
// cols -> coalesced 16B loads; zero unpack VALU.
template<bool XY>
__device__ __forceinline__ void window_loop(
    const float4* __restrict__ gPb, const float4* __restrict__ gQb,
    const float* c0s, const float* c1s, const float* c2s, const float* mA,
    bool xy_on, float dy2, float fi0, float eg[Gc][3])
{
#pragma unroll
    for (int r = 0; r < 3; ++r) {               // prologue (triangular): c <= r
        row_taps<XY>(gPb[(size_t)r * PW], gQb[(size_t)r * PW], r,
                     c0s, c1s, c2s, mA, xy_on, dy2, fi0, eg, 0, r);
    }
#pragma unroll 2
    for (int r = 3; r <= 22; ++r) {             // full rows: all 4 centers
        row_taps<XY>(gPb[(size_t)r * PW], gQb[(size_t)r * PW], r,
                     c0s, c1s, c2s, mA, xy_on, dy2, fi0, eg, 0, 3);
    }
#pragma unroll
    for (int r = 23; r <= 25; ++r) {            // epilogue (triangular): c >= r-22
        row_taps<XY>(gPb[(size_t)r * PW], gQb[(size_t)r * PW], r,
                     c0s, c1s, c2s, mA, xy_on, dy2, fi0, eg, r - 22, 3);
    }
}

// Window kernel, LDS-free, fp32 records. Grid: (5, 5*B, 23) = 1150 blocks.
// Block (32,8). gP/gQ (2.1 MB) fully L2-resident; no staging, no barrier.
// Spread-cell reduction unchanged.
__global__ __launch_bounds__(256, 5) void gcrf_kernel(
    const float4* __restrict__ gP, const float4* __restrict__ gQ,
    const float4* __restrict__ cvec, float* __restrict__ cells)
{
    int tx = threadIdx.x;                 // 0..31 (j)
    int ty = threadIdx.y;                 // 0..7  (i-group)
    int tid = ty * TJ + tx;
    int jx = blockIdx.x;
    int j  = jx * TJ + tx;
    int by = blockIdx.y;
    int b  = by / 5;
    int it = by - b * 5;
    int i0g = it * TI + ty * Gc;          // first center row of this thread
    int dj = blockIdx.z;                  // 0..22

    size_t woff = (size_t)b * PP + (size_t)i0g * PW + (size_t)(jx * TJ + dj) + tx;
    const float4* gPb = gP + woff;        // window base (local row 0)
    const float4* gQb = gQ + woff;
    // center base: padded row i0g + SPANc, padded col j + SPANc
    const float4* gC = gP + (size_t)b * PP + (size_t)(i0g + SPANc) * PW
                          + (size_t)(j + SPANc);

    bool isxy = (jx == 0 && it == 0);     // block-uniform

    float c0s[Gc], c1s[Gc], c2s[Gc], mA[Gc], kAe[Gc];
#pragma unroll
    for (int c = 0; c < Gc; ++c) {
        float4 cu = gC[(size_t)c * PW];
        c0s[c] = cu.x * CX; c1s[c] = cu.y * CX; c2s[c] = cu.z * CX;
        mA[c] = -CA * fmaf(cu.x, cu.x, fmaf(cu.y, cu.y, cu.z * cu.z));
        kAe[c] = isxy ? 1.0f : __builtin_amdgcn_exp2f(mA[c]);
    }

    // k_xy < 2.3e-29 unless both i<16 and j<16 (source-bug form: d = c - p/6)
    bool xy_on = (j < 16) && (i0g < 16);
    float dy = (float)j - (float)(j + dj - SPANc) * (1.0f / 6.0f);
    float dy2 = dy * dy;
    float fi0 = (float)i0g;

    float eg[Gc][3];
#pragma unroll
    for (int c = 0; c < Gc; ++c) { eg[c][0] = 0.f; eg[c][1] = 0.f; eg[c][2] = 0.f; }

    if (isxy) {   // only blocks where xy_on can hold
        window_loop<true>(gPb, gQb, c0s, c1s, c2s, mA, xy_on, dy2, fi0, eg);
    } else {
        window_loop<false>(gPb, gQb, c0s, c1s, c2s, mA, false, dy2, fi0, eg);
    }

    // epilogue: cvec holds lam*(1-dst)*(1-y_c)/(B*HW); kAe folds back exp2(mA)
    const float4* cv = cvec + ((size_t)b * HWn + (size_t)i0g * Wn + j);
    float contrib = 0.0f;
#pragma unroll
    for (int c = 0; c < Gc; ++c) {
        float4 t = cv[(size_t)c * Wn];
        float d = eg[c][0] * t.x + eg[c][1] * t.y + eg[c][2] * t.z;
        contrib = fmaf(kAe[c], d, contrib);
    }

    float v = wave_reduce64(contrib);
    __shared__ float wsum[4];
    if ((tid & 63) == 0) wsum[tid >> 6] = v;
    __syncthreads();
    if (tid == 0) {
        int bflat = (blockIdx.z * gridDim.y + blockIdx.y) * gridDim.x + blockIdx.x;
        atomicAdd(cells + (size_t)(bflat & (NCELL - 1)) * CELLSTRIDE,
                  wsum[0] + wsum[1] + wsum[2] + wsum[3]);
    }
}

// Single-wave finalize: sum 64 spread cells + 259 CE partials, plain-store out.
__global__ __launch_bounds__(64) void finalize_kernel(
    const float* __restrict__ cells, const float* __restrict__ pc,
    float* __restrict__ out)
{
    int t = threadIdx.x;
    float s = cells[(size_t)t * CELLSTRIDE];
    for (int k = t; k < NPREP; k += 64) s += pc[k];
    float v = wave_reduce64(s);
    if (t == 0) out[0] = v;
}

extern "C" void kernel_launch(void* const* d_in, const int* in_sizes, int n_in,
                              void* d_out, int out_size, void* d_ws, size_t ws_size,
                              hipStream_t stream)
{
    const float* logit  = (const float*)d_in[0];
    const int*   target = (const int*)d_in[1];
    const float* image  = (const float*)d_in[2];
    const float* srcmap = (const float*)d_in[3];
    const float* dstmap = (const float*)d_in[4];
    float* out = (float*)d_out;

    const size_t NRECG = (size_t)Bn * PP;   // 66,248 padded records
    float*  pc    = (float*)((char*)d_ws + 256);                 // 259 CE partials
    float*  cells = (float*)((char*)d_ws + 4096);                // 64 cells, 256 B apart
    float4* gP    = (float4*)((char*)d_ws + 4096 + 16384);
    float4* gQ    = gP + NRECG;
    float4* cvec  = gQ + NRECG;

    prep_kernel<<<NPREP, 256, 0, stream>>>(logit, target, image, srcmap, dstmap,
                                           gP, gQ, cvec, pc, cells);
    dim3 grid(Wn / TJ, (Hn / TI) * Bn, Kc);
    dim3 blk(TJ, 8);
    gcrf_kernel<<<grid, blk, 0, stream>>>(gP, gQ, cvec, cells);
    finalize_kernel<<<1, 64, 0, stream>>>(cells, pc, out);
}

// Round 14
// 80.422 us; speedup vs baseline: 1.0240x; 1.0240x over previous
//
#include <hip/hip_runtime.h>

#define Bn 2
#define Cn 3
#define Hn 160
#define Wn 160
#define SPANc 11
#define Kc 23
#define HWn (Hn * Wn)
#define PW 182                 // padded dim: 160 + 2*11
#define PP (PW * PW)
#define LAMc 0.15f
#define INVN (1.0f / (float)(Bn * HWn))
#define TJ 32                  // j-tile width (= lanes 0..31)
#define Gc 2                   // centers per thread (vertical)
#define TI 16                  // i-tile height = 8 ty-groups * Gc
#define DJW 3                  // dj values served per block
#define NDJG 8                 // dj groups (8*3 = 24 >= 23)
#define TROW (TI + Kc - 1)     // 38 staged rows
#define TCOL (TJ + DJW - 1 + 0)// 34 staged cols (tx + l, tx<=31, l<=2)
#define NREC (TROW * TCOL)     // 1292 records (16 B each = 20.7 KB LDS)
#define CEXP (-0.72134752f)    // -0.5 * log2(e)
#define CX   (14.42695041f)    // 20 * 0.72134752  (cross-term scale)
#define CA   (0.72134752f)
#define NPREP ((Bn * PP + 255) / 256)   // 259 prep blocks
#define NCELL 64               // spread accumulator cells (256 B apart)
#define CELLSTRIDE 64          // floats between cells

__device__ __forceinline__ float wave_reduce64(float v) {
#pragma unroll
    for (int off = 32; off > 0; off >>= 1) v += __shfl_down(v, off, 64);
    return v;
}

// pack two floats as bf16 (rne) into one uint: a in high 16, b in low 16
__device__ __forceinline__ unsigned int bf16pk(float a, float b) {
    unsigned int ua = __float_as_uint(a), ub = __float_as_uint(b);
    ua += 0x7fffu + ((ua >> 16) & 1u);
    ub += 0x7fffu + ((ub >> 16) & 1u);
    return (ua & 0xffff0000u) | (ub >> 16);
}

// Fused prep (R12-proven): zero halo + softmax/pack interior + CE partials +
// zero spread cells. Record uint4: [pk(p0,p1), pk(p2,mB), pk(q0,q1), pk(q2,0)]
__global__ __launch_bounds__(256) void prep_kernel(
    const float* __restrict__ logit, const int* __restrict__ target,
    const float* __restrict__ image, const float* __restrict__ srcmap,
    const float* __restrict__ dstmap, uint4* __restrict__ gU4,
    float4* __restrict__ cvec, float* __restrict__ pc, float* __restrict__ cells)
{
    int idx = blockIdx.x * 256 + threadIdx.x;
    float ce = 0.0f;
    if (idx < NCELL) cells[idx * CELLSTRIDE] = 0.0f;   // gcrf runs after (stream order)
    if (idx < Bn * PP) {
        int b   = idx / PP;
        int rem = idx - b * PP;
        int ip  = rem / PW;
        int jp  = rem - ip * PW;
        int i = ip - SPANc, j = jp - SPANc;
        if ((unsigned)i < (unsigned)Hn && (unsigned)j < (unsigned)Wn) {
            int r = i * Wn + j;
            int p = b * HWn + r;
            const float* lg = logit + (size_t)b * Cn * HWn + r;
            float l0 = lg[0], l1 = lg[HWn], l2 = lg[2 * HWn];
            float m = fmaxf(l0, fmaxf(l1, l2));
            float e0 = __expf(l0 - m), e1 = __expf(l1 - m), e2 = __expf(l2 - m);
            float s = e0 + e1 + e2;
            float inv = 1.0f / s;
            float y0 = e0 * inv, y1 = e1 * inv, y2 = e2 * inv;
            float lse = m + __logf(s);

            const float* im = image + (size_t)b * 3 * HWn + r;
            float p0 = im[0], p1 = im[HWn], p2 = im[2 * HWn];
            float sv = srcmap[p];
            float dv = dstmap[p];

            float B = (p0 * p0 + p1 * p1 + p2 * p2) * (100.0f * CA);
            gU4[idx] = make_uint4(bf16pk(p0, p1), bf16pk(p2, -B),
                                  bf16pk(sv * y0, sv * y1), bf16pk(sv * y2, 0.0f));

            float md = LAMc * (1.0f - dv) * INVN;
            cvec[p] = make_float4(md * (1.0f - y0), md * (1.0f - y1),
                                  md * (1.0f - y2), 0.0f);

            int t = target[p];
            float lt = (t == 0) ? l0 : ((t == 1) ? l1 : l2);
            ce = (lse - lt) * dv * INVN;
        } else {
            gU4[idx] = make_uint4(0u, 0u, 0u, 0u);
        }
    }

    float v = wave_reduce64(ce);
    __shared__ float wsum[4];
    int tid = threadIdx.x;
    if ((tid & 63) == 0) wsum[tid >> 6] = v;
    __syncthreads();
    if (tid == 0) pc[blockIdx.x] = wsum[0] + wsum[1] + wsum[2] + wsum[3];
}

// One tap (proven scalar form). Non-XY: kA-factored — k = exp2(c.p + mB);
// per-center exp2(mA) applied once in the epilogue. XY: exact form + xy term.
template<bool XY>
__device__ __forceinline__ void tap(float p0, float p1, float p2, float mB,
                                    float q0, float q1, float q2,
                                    float c0s, float c1s, float c2s, float mA,
                                    bool xy_on, float dy2, float dxv,
                                    float& e0, float& e1, float& e2)
{
    float e = fmaf(c0s, p0, fmaf(c1s, p1, fmaf(c2s, p2, mB)));
    float k;
    if constexpr (XY) {
        k = __builtin_amdgcn_exp2f(e + mA);
        if (xy_on) k += __builtin_amdgcn_exp2f(fmaf(dxv, dxv, dy2) * CEXP);
    } else {
        k = __builtin_amdgcn_exp2f(e);
    }
    e0 = fmaf(k, q0, e0);
    e1 = fmaf(k, q1, e1);
    e2 = fmaf(k, q2, e2);
}

// Row for Gc=2 (R5-proven): local row r = c + di, di = r - c in [0,22].
template<bool XY>
__device__ __forceinline__ void row_taps(uint4 ru, int r,
    const float* c0s, const float* c1s, const float* c2s, const float* mA,
    bool xy_on, float dy2, float fi0, float eg[Gc][3], int clo, int chi)
{
    float p0 = __uint_as_float(ru.x & 0xffff0000u);
    float p1 = __uint_as_float(ru.x << 16);
    float p2 = __uint_as_float(ru.y & 0xffff0000u);
    float mB = __uint_as_float(ru.y << 16);
    float q0 = __uint_as_float(ru.z & 0xffff0000u);
    float q1 = __uint_as_float(ru.z << 16);
    float q2 = __uint_as_float(ru.w & 0xffff0000u);
    float dxb = XY ? (fi0 - (fi0 + (float)(r - SPANc)) * (1.0f / 6.0f)) : 0.0f;
#pragma unroll
    for (int c = 0; c < Gc; ++c) {
        if (c < clo || c > chi) continue;
        tap<XY>(p0, p1, p2, mB, q0, q1, q2, c0s[c], c1s[c], c2s[c], mA[c],
                xy_on, dy2, dxb + (float)c, eg[c][0], eg[c][1], eg[c][2]);
    }
}

// Window sweep over the DJW dj values served by this block's staged tile.
// Per dj: thread reads its vertical strip (local col tx + l), rows 0..23.
// Accumulators are shared across dj (linear sum; kAe is per-center).
template<bool XY>
__device__ __forceinline__ void window_sweep(
    const uint4* sU4, int ty, int tx, int j, int djg,
    const float* c0s, const float* c1s, const float* c2s, const float* mA,
    bool xy_on, float fi0, float eg[Gc][3])
{
#pragma unroll 1
    for (int l = 0; l < DJW; ++l) {
        int dj = djg * DJW + l;
        if (dj >= Kc) break;               // block-uniform guard (last group)
        float dy = XY ? ((float)j - (float)(j + dj - SPANc) * (1.0f / 6.0f)) : 0.0f;
        float dy2 = dy * dy;
        int lbase = (ty * Gc) * TCOL + tx + l;
        row_taps<XY>(sU4[lbase], 0, c0s, c1s, c2s, mA,
                     xy_on, dy2, fi0, eg, 0, 0);
#pragma unroll 2
        for (int r = 1; r <= 22; ++r) {    // full rows: both centers
            row_taps<XY>(sU4[lbase + r * TCOL], r, c0s, c1s, c2s, mA,
                         xy_on, dy2, fi0, eg, 0, 1);
        }
        row_taps<XY>(sU4[lbase + 23 * TCOL], 23, c0s, c1s, c2s, mA,
                     xy_on, dy2, fi0, eg, 1, 1);
    }
}

// Window kernel, multi-dj tile. Grid: (5, 10*B, 8) = 800 blocks. Block (32,8).
// One dj-TRIPLE per block: stage 38x34 records (20.7 KB LDS) once, sweep 3 dj
// from it — staging per dj drops 6.75 -> 1.7 loads/thread, center preamble /3.
// Taps, tap math, spread-cell reduction unchanged from the proven baseline.
__global__ __launch_bounds__(256, 5) void gcrf_kernel(
    const uint4* __restrict__ gU4, const float4* __restrict__ cvec,
    float* __restrict__ cells)
{
    __shared__ uint4 sU4[NREC];

    int tx = threadIdx.x;                 // 0..31 (j)
    int ty = threadIdx.y;                 // 0..7  (i-group)
    int tid = ty * TJ + tx;
    int jx = blockIdx.x;
    int j  = jx * TJ + tx;
    int by = blockIdx.y;
    int b  = by / 10;
    int it = by - b * 10;
    int i0g = it * TI + ty * Gc;          // first center row of this thread
    int djg = blockIdx.z;                 // 0..7 (dj group)

    // ---- stage 38x34 tile: origin padded row it*TI, padded col jx*TJ + djg*DJW
    int cbase = jx * TJ + djg * DJW;
    int ccmax = (PW - 1) - cbase;         // clamp (only binds at jx=4,djg=7; unread)
    size_t g0 = (size_t)b * PP + (size_t)(it * TI) * PW + cbase;
    for (int n = tid; n < NREC; n += 256) {
        int rr = n / TCOL, cc = n - rr * TCOL;
        int ccl = (cc < ccmax) ? cc : ccmax;
        sU4[n] = gU4[g0 + (size_t)rr * PW + ccl];
    }
    __syncthreads();

    bool isxy = (jx == 0 && it == 0);     // block-uniform

    // center consts straight from global (L2-hot), R12 pattern
    const uint4* gC = gU4 + (size_t)b * PP + (size_t)(i0g + SPANc) * PW
                          + (size_t)(j + SPANc);
    float c0s[Gc], c1s[Gc], c2s[Gc], mA[Gc], kAe[Gc];
#pragma unroll
    for (int c = 0; c < Gc; ++c) {
        uint4 cu = gC[(size_t)c * PW];
        float cc0 = __uint_as_float(cu.x & 0xffff0000u);
        float cc1 = __uint_as_float(cu.x << 16);
        float cc2 = __uint_as_float(cu.y & 0xffff0000u);
        c0s[c] = cc0 * CX; c1s[c] = cc1 * CX; c2s[c] = cc2 * CX;
        mA[c] = -CA * fmaf(cc0, cc0, fmaf(cc1, cc1, cc2 * cc2));
        kAe[c] = isxy ? 1.0f : __builtin_amdgcn_exp2f(mA[c]);
    }

    // k_xy < 2.3e-29 unless both i<16 and j<16 (source-bug form: d = c - p/6)
    bool xy_on = (j < 16) && (i0g < 16);
    float fi0 = (float)i0g;

    float eg[Gc][3];
#pragma unroll
    for (int c = 0; c < Gc; ++c) { eg[c][0] = 0.f; eg[c][1] = 0.f; eg[c][2] = 0.f; }

    if (isxy) {   // only blocks where xy_on can hold
        window_sweep<true>(sU4, ty, tx, j, djg, c0s, c1s, c2s, mA, xy_on, fi0, eg);
    } else {
        window_sweep<false>(sU4, ty, tx, j, djg, c0s, c1s, c2s, mA, false, fi0, eg);
    }

    // epilogue: cvec holds lam*(1-dst)*(1-y_c)/(B*HW); kAe folds back exp2(mA)
    const float4* cv = cvec + ((size_t)b * HWn + (size_t)i0g * Wn + j);
    float contrib = 0.0f;
#pragma unroll
    for (int c = 0; c < Gc; ++c) {
        float4 t = cv[(size_t)c * Wn];
        float d = eg[c][0] * t.x + eg[c][1] * t.y + eg[c][2] * t.z;
        contrib = fmaf(kAe[c], d, contrib);
    }

    float v = wave_reduce64(contrib);
    __shared__ float wsum[4];
    if ((tid & 63) == 0) wsum[tid >> 6] = v;
    __syncthreads();
    if (tid == 0) {
        int bflat = (blockIdx.z * gridDim.y + blockIdx.y) * gridDim.x + blockIdx.x;
        atomicAdd(cells + (size_t)(bflat & (NCELL - 1)) * CELLSTRIDE,
                  wsum[0] + wsum[1] + wsum[2] + wsum[3]);
    }
}

// Single-wave finalize: sum 64 spread cells + 259 CE partials, plain-store out.
__global__ __launch_bounds__(64) void finalize_kernel(
    const float* __restrict__ cells, const float* __restrict__ pc,
    float* __restrict__ out)
{
    int t = threadIdx.x;
    float s = cells[(size_t)t * CELLSTRIDE];
    for (int k = t; k < NPREP; k += 64) s += pc[k];
    float v = wave_reduce64(s);
    if (t == 0) out[0] = v;
}

extern "C" void kernel_launch(void* const* d_in, const int* in_sizes, int n_in,
                              void* d_out, int out_size, void* d_ws, size_t ws_size,
                              hipStream_t stream)
{
    const float* logit  = (const float*)d_in[0];
    const int*   target = (const int*)d_in[1];
    const float* image  = (const float*)d_in[2];
    const float* srcmap = (const float*)d_in[3];
    const float* dstmap = (const float*)d_in[4];
    float* out = (float*)d_out;

    const size_t NRECG = (size_t)Bn * PP;   // 66,248 padded records
    float*  pc    = (float*)((char*)d_ws + 256);                 // 259 CE partials
    float*  cells = (float*)((char*)d_ws + 4096);                // 64 cells, 256 B apart
    uint4*  gU4   = (uint4*)((char*)d_ws + 4096 + 16384);
    float4* cvec  = (float4*)((char*)d_ws + 4096 + 16384 + NRECG * 16);

    prep_kernel<<<NPREP, 256, 0, stream>>>(logit, target, image, srcmap, dstmap,
                                           gU4, cvec, pc, cells);
    dim3 grid(Wn / TJ, (Hn / TI) * Bn, NDJG);
    dim3 blk(TJ, 8);
    gcrf_kernel<<<grid, blk, 0, stream>>>(gU4, cvec, cells);
    finalize_kernel<<<1, 64, 0, stream>>>(cells, pc, out);
}

// Round 15
// 79.359 us; speedup vs baseline: 1.0377x; 1.0134x over previous
//
#include <hip/hip_runtime.h>

#define Bn 2
#define Cn 3
#define Hn 160
#define Wn 160
#define SPANc 11
#define Kc 23
#define HWn (Hn * Wn)
#define PW 182                 // padded dim: 160 + 2*11
#define PP (PW * PW)
#define LAMc 0.15f
#define INVN (1.0f / (float)(Bn * HWn))
#define TJ 32                  // j-tile width (= lanes 0..31)
#define Gc 4                   // centers per thread (vertical)
#define TI 32                  // i-tile height = 8 ty-groups * Gc
#define CEXP (-0.72134752f)    // -0.5 * log2(e)
#define CX   (14.42695041f)    // 20 * 0.72134752  (cross-term scale)
#define CA   (0.72134752f)
#define NPREP ((Bn * PP + 255) / 256)   // 259 prep blocks
#define NCELL 64               // spread accumulator cells (256 B apart)
#define CELLSTRIDE 64          // floats between cells

__device__ __forceinline__ float wave_reduce64(float v) {
#pragma unroll
    for (int off = 32; off > 0; off >>= 1) v += __shfl_down(v, off, 64);
    return v;
}

// pack two floats as bf16 (rne) into one uint: a in high 16, b in low 16
__device__ __forceinline__ unsigned int bf16pk(float a, float b) {
    unsigned int ua = __float_as_uint(a), ub = __float_as_uint(b);
    ua += 0x7fffu + ((ua >> 16) & 1u);
    ub += 0x7fffu + ((ub >> 16) & 1u);
    return (ua & 0xffff0000u) | (ub >> 16);
}

// Fused: zero halo + softmax/pack interior + CE block-partials (pre-scaled) +
// zero the 64 spread cells. Record uint4: [pk(p0,p1), pk(p2,mB), pk(q0,q1), pk(q2,0)]
__global__ __launch_bounds__(256) void prep_kernel(
    const float* __restrict__ logit, const int* __restrict__ target,
    const float* __restrict__ image, const float* __restrict__ srcmap,
    const float* __restrict__ dstmap, uint4* __restrict__ gU4,
    float4* __restrict__ cvec, float* __restrict__ pc, float* __restrict__ cells)
{
    int idx = blockIdx.x * 256 + threadIdx.x;
    float ce = 0.0f;
    if (idx < NCELL) cells[idx * CELLSTRIDE] = 0.0f;   // gcrf runs after (stream order)
    if (idx < Bn * PP) {
        int b   = idx / PP;
        int rem = idx - b * PP;
        int ip  = rem / PW;
        int jp  = rem - ip * PW;
        int i = ip - SPANc, j = jp - SPANc;
        if ((unsigned)i < (unsigned)Hn && (unsigned)j < (unsigned)Wn) {
            int r = i * Wn + j;
            int p = b * HWn + r;
            const float* lg = logit + (size_t)b * Cn * HWn + r;
            float l0 = lg[0], l1 = lg[HWn], l2 = lg[2 * HWn];
            float m = fmaxf(l0, fmaxf(l1, l2));
            float e0 = __expf(l0 - m), e1 = __expf(l1 - m), e2 = __expf(l2 - m);
            float s = e0 + e1 + e2;
            float inv = 1.0f / s;
            float y0 = e0 * inv, y1 = e1 * inv, y2 = e2 * inv;
            float lse = m + __logf(s);

            const float* im = image + (size_t)b * 3 * HWn + r;
            float p0 = im[0], p1 = im[HWn], p2 = im[2 * HWn];
            float sv = srcmap[p];
            float dv = dstmap[p];

            float B = (p0 * p0 + p1 * p1 + p2 * p2) * (100.0f * CA);
            gU4[idx] = make_uint4(bf16pk(p0, p1), bf16pk(p2, -B),
                                  bf16pk(sv * y0, sv * y1), bf16pk(sv * y2, 0.0f));

            float md = LAMc * (1.0f - dv) * INVN;
            cvec[p] = make_float4(md * (1.0f - y0), md * (1.0f - y1),
                                  md * (1.0f - y2), 0.0f);

            int t = target[p];
            float lt = (t == 0) ? l0 : ((t == 1) ? l1 : l2);
            ce = (lse - lt) * dv * INVN;
        } else {
            gU4[idx] = make_uint4(0u, 0u, 0u, 0u);
        }
    }

    float v = wave_reduce64(ce);
    __shared__ float wsum[4];
    int tid = threadIdx.x;
    if ((tid & 63) == 0) wsum[tid >> 6] = v;
    __syncthreads();
    if (tid == 0) pc[blockIdx.x] = wsum[0] + wsum[1] + wsum[2] + wsum[3];
}

// One tap (proven scalar form). Non-XY: kA-factored — k = exp2(c.p + mB);
// per-center exp2(mA) applied once in the epilogue. XY: exact form + xy term.
template<bool XY>
__device__ __forceinline__ void tap(float p0, float p1, float p2, float mB,
                                    float q0, float q1, float q2,
                                    float c0s, float c1s, float c2s, float mA,
                                    bool xy_on, float dy2, float dxv,
                                    float& e0, float& e1, float& e2)
{
    float e = fmaf(c0s, p0, fmaf(c1s, p1, fmaf(c2s, p2, mB)));
    float k;
    if constexpr (XY) {
        k = __builtin_amdgcn_exp2f(e + mA);
        if (xy_on) k += __builtin_amdgcn_exp2f(fmaf(dxv, dxv, dy2) * CEXP);
    } else {
        k = __builtin_amdgcn_exp2f(e);
    }
    e0 = fmaf(k, q0, e0);
    e1 = fmaf(k, q1, e1);
    e2 = fmaf(k, q2, e2);
}

template<bool XY>
__device__ __forceinline__ void row_taps(uint4 ru, int r,
    const float* c0s, const float* c1s, const float* c2s, const float* mA,
    bool xy_on, float dy2, float fi0, float eg[Gc][3], int clo, int chi)
{
    float p0 = __uint_as_float(ru.x & 0xffff0000u);
    float p1 = __uint_as_float(ru.x << 16);
    float p2 = __uint_as_float(ru.y & 0xffff0000u);
    float mB = __uint_as_float(ru.y << 16);
    float q0 = __uint_as_float(ru.z & 0xffff0000u);
    float q1 = __uint_as_float(ru.z << 16);
    float q2 = __uint_as_float(ru.w & 0xffff0000u);
    float dxb = XY ? (fi0 - (fi0 + (float)(r - SPANc)) * (1.0f / 6.0f)) : 0.0f;
#pragma unroll
    for (int c = 0; c < Gc; ++c) {
        if (c < clo || c > chi) continue;
        tap<XY>(p0, p1, p2, mB, q0, q1, q2, c0s[c], c1s[c], c2s[c], mA[c],
                xy_on, dy2, dxb + (float)c, eg[c][0], eg[c][1], eg[c][2]);
    }
}

// 3-phase window loop reading rows DIRECTLY from global (L2-resident gU4).
// gbase points at this thread's local row 0 (padded row i0g, padded col
// jx*TJ + dj + tx); rows stride PW. Lane-consecutive cols -> coalesced loads.
template<bool XY>
__device__ __forceinline__ void window_loop(
    const uint4* __restrict__ gbase,
    const float* c0s, const float* c1s, const float* c2s, const float* mA,
    bool xy_on, float dy2, float fi0, float eg[Gc][3])
{
#pragma unroll
    for (int r = 0; r < 3; ++r) {               // prologue (triangular): c <= r
        row_taps<XY>(gbase[(size_t)r * PW], r, c0s, c1s, c2s, mA,
                     xy_on, dy2, fi0, eg, 0, r);
    }
#pragma unroll 2
    for (int r = 3; r <= 22; ++r) {             // full rows: all 4 centers
        row_taps<XY>(gbase[(size_t)r * PW], r, c0s, c1s, c2s, mA,
                     xy_on, dy2, fi0, eg, 0, 3);
    }
#pragma unroll
    for (int r = 23; r <= 25; ++r) {            // epilogue (triangular): c >= r-22
        row_taps<XY>(gbase[(size_t)r * PW], r, c0s, c1s, c2s, mA,
                     xy_on, dy2, fi0, eg, r - 22, 3);
    }
}

// Window kernel, LDS-FREE. Grid: (5, 5*B, 23) = 1150 blocks. Block (32,8).
// gU4 (1.06 MB) is fully L2-resident; each thread reads its 26 window records
// + 4 center records directly from global — no staging, no __syncthreads,
// no LDS. Spread-cell reduction unchanged.
__global__ __launch_bounds__(256, 5) void gcrf_kernel(
    const uint4* __restrict__ gU4, const float4* __restrict__ cvec,
    float* __restrict__ cells)
{
    int tx = threadIdx.x;                 // 0..31 (j)
    int ty = threadIdx.y;                 // 0..7  (i-group)
    int tid = ty * TJ + tx;
    int jx = blockIdx.x;
    int j  = jx * TJ + tx;
    int by = blockIdx.y;
    int b  = by / 5;
    int it = by - b * 5;
    int i0g = it * TI + ty * Gc;          // first center row of this thread
    int dj = blockIdx.z;                  // 0..22

    // window base: padded row i0g (= interior i0g - SPANc), padded col j + dj - SPANc
    const uint4* gbase = gU4 + (size_t)b * PP + (size_t)i0g * PW
                             + (size_t)(jx * TJ + dj) + tx;
    // center base: padded row i0g + SPANc, padded col j + SPANc
    const uint4* gC = gU4 + (size_t)b * PP + (size_t)(i0g + SPANc) * PW
                          + (size_t)(j + SPANc);

    bool isxy = (jx == 0 && it == 0);     // block-uniform

    float c0s[Gc], c1s[Gc], c2s[Gc], mA[Gc], kAe[Gc];
#pragma unroll
    for (int c = 0; c < Gc; ++c) {
        uint4 cu = gC[(size_t)c * PW];
        float cc0 = __uint_as_float(cu.x & 0xffff0000u);
        float cc1 = __uint_as_float(cu.x << 16);
        float cc2 = __uint_as_float(cu.y & 0xffff0000u);
        c0s[c] = cc0 * CX; c1s[c] = cc1 * CX; c2s[c] = cc2 * CX;
        mA[c] = -CA * fmaf(cc0, cc0, fmaf(cc1, cc1, cc2 * cc2));
        kAe[c] = isxy ? 1.0f : __builtin_amdgcn_exp2f(mA[c]);
    }

    // k_xy < 2.3e-29 unless both i<16 and j<16 (source-bug form: d = c - p/6)
    bool xy_on = (j < 16) && (i0g < 16);
    float dy = (float)j - (float)(j + dj - SPANc) * (1.0f / 6.0f);
    float dy2 = dy * dy;
    float fi0 = (float)i0g;

    float eg[Gc][3];
#pragma unroll
    for (int c = 0; c < Gc; ++c) { eg[c][0] = 0.f; eg[c][1] = 0.f; eg[c][2] = 0.f; }

    if (isxy) {   // only blocks where xy_on can hold
        window_loop<true>(gbase, c0s, c1s, c2s, mA, xy_on, dy2, fi0, eg);
    } else {
        window_loop<false>(gbase, c0s, c1s, c2s, mA, false, dy2, fi0, eg);
    }

    // epilogue: cvec holds lam*(1-dst)*(1-y_c)/(B*HW); kAe folds back exp2(mA)
    const float4* cv = cvec + ((size_t)b * HWn + (size_t)i0g * Wn + j);
    float contrib = 0.0f;
#pragma unroll
    for (int c = 0; c < Gc; ++c) {
        float4 t = cv[(size_t)c * Wn];
        float d = eg[c][0] * t.x + eg[c][1] * t.y + eg[c][2] * t.z;
        contrib = fmaf(kAe[c], d, contrib);
    }

    float v = wave_reduce64(contrib);
    __shared__ float wsum[4];
    if ((tid & 63) == 0) wsum[tid >> 6] = v;
    __syncthreads();
    if (tid == 0) {
        int bflat = (blockIdx.z * gridDim.y + blockIdx.y) * gridDim.x + blockIdx.x;
        atomicAdd(cells + (size_t)(bflat & (NCELL - 1)) * CELLSTRIDE,
                  wsum[0] + wsum[1] + wsum[2] + wsum[3]);
    }
}

// Single-wave finalize: sum 64 spread cells + 259 CE partials, plain-store out.
__global__ __launch_bounds__(64) void finalize_kernel(
    const float* __restrict__ cells, const float* __restrict__ pc,
    float* __restrict__ out)
{
    int t = threadIdx.x;
    float s = cells[(size_t)t * CELLSTRIDE];
    for (int k = t; k < NPREP; k += 64) s += pc[k];
    float v = wave_reduce64(s);
    if (t == 0) out[0] = v;
}

extern "C" void kernel_launch(void* const* d_in, const int* in_sizes, int n_in,
                              void* d_out, int out_size, void* d_ws, size_t ws_size,
                              hipStream_t stream)
{
    const float* logit  = (const float*)d_in[0];
    const int*   target = (const int*)d_in[1];
    const float* image  = (const float*)d_in[2];
    const float* srcmap = (const float*)d_in[3];
    const float* dstmap = (const float*)d_in[4];
    float* out = (float*)d_out;

    const size_t NRECG = (size_t)Bn * PP;   // 66,248 padded records
    float*  pc    = (float*)((char*)d_ws + 256);                 // 259 CE partials
    float*  cells = (float*)((char*)d_ws + 4096);                // 64 cells, 256 B apart
    uint4*  gU4   = (uint4*)((char*)d_ws + 4096 + 16384);
    float4* cvec  = (float4*)((char*)d_ws + 4096 + 16384 + NRECG * 16);

    prep_kernel<<<NPREP, 256, 0, stream>>>(logit, target, image, srcmap, dstmap,
                                           gU4, cvec, pc, cells);
    dim3 grid(Wn / TJ, (Hn / TI) * Bn, Kc);
    dim3 blk(TJ, 8);
    gcrf_kernel<<<grid, blk, 0, stream>>>(gU4, cvec, cells);
    finalize_kernel<<<1, 64, 0, stream>>>(cells, pc, out);
}